// Round 1
// baseline (810.516 us; speedup 1.0000x reference)
//
#include <hip/hip_runtime.h>
#include <hip/hip_bf16.h>
#include <cstddef>

#define B_  8
#define S_  512
#define HID 1024
#define H_  16
#define D_  64

// ---------------------------------------------------------------------------
// Kernel A: fused QKV projection.  Y = X @ W^T + b  for W in {Wq, Wk, Wv}
// (blockIdx.z selects which).  Q and V are written as [B,H,S,D]; K is written
// TRANSPOSED as [B,H,D,S] (via an LDS transpose) so the attention kernel can
// read K rows coalesced along the k dimension.
// 64x64 output tile per 256-thread block, 4x4 microtile per thread,
// k-major LDS tiles so fragment reads are ds_read_b128.
// ---------------------------------------------------------------------------
__global__ __launch_bounds__(256) void qkv_gemm_kernel(
    const float* __restrict__ X,
    const float* __restrict__ Wq, const float* __restrict__ bq,
    const float* __restrict__ Wk, const float* __restrict__ bk,
    const float* __restrict__ Wv, const float* __restrict__ bv,
    float* __restrict__ Q, float* __restrict__ Kt, float* __restrict__ V)
{
    const int which = blockIdx.z;
    const float* __restrict__ W    = (which == 0) ? Wq : (which == 1) ? Wk : Wv;
    const float* __restrict__ bias = (which == 0) ? bq : (which == 1) ? bk : bv;

    __shared__ float Xs[16][68];   // [kk][row], pad 68 -> conflict-free b128 reads
    __shared__ float Ws[16][68];
    __shared__ float tbuf[64][65]; // transpose staging for the K epilogue

    const int tid  = threadIdx.x;
    const int tx   = tid & 15;
    const int ty   = tid >> 4;
    const int m0   = blockIdx.y * 64;
    const int n0   = blockIdx.x * 64;
    const int lrow = tid >> 2;        // 0..63
    const int lcol = (tid & 3) * 4;   // 0,4,8,12

    float c[4][4] = {};

    const float* xp = &X[(size_t)(m0 + lrow) * HID + lcol];
    const float* wp = &W[(size_t)(n0 + lrow) * HID + lcol];

    for (int k0 = 0; k0 < HID; k0 += 16) {
        float4 xv = *(const float4*)(xp + k0);
        float4 wv = *(const float4*)(wp + k0);
        __syncthreads();
        Xs[lcol + 0][lrow] = xv.x;
        Xs[lcol + 1][lrow] = xv.y;
        Xs[lcol + 2][lrow] = xv.z;
        Xs[lcol + 3][lrow] = xv.w;
        Ws[lcol + 0][lrow] = wv.x;
        Ws[lcol + 1][lrow] = wv.y;
        Ws[lcol + 2][lrow] = wv.z;
        Ws[lcol + 3][lrow] = wv.w;
        __syncthreads();
        #pragma unroll
        for (int kk = 0; kk < 16; ++kk) {
            float4 av  = *(const float4*)&Xs[kk][ty * 4];
            float4 bv4 = *(const float4*)&Ws[kk][tx * 4];
            float a[4]  = {av.x, av.y, av.z, av.w};
            float bb[4] = {bv4.x, bv4.y, bv4.z, bv4.w};
            #pragma unroll
            for (int i = 0; i < 4; ++i)
                #pragma unroll
                for (int j = 0; j < 4; ++j)
                    c[i][j] = fmaf(a[i], bb[j], c[i][j]);
        }
    }

    const int bb_ = m0 >> 9;   // batch  (64 | 512, so tile is within one b)
    const int hh  = n0 >> 6;   // head   (tile is exactly one head's 64 cols)

    if (which != 1) {
        // Q and V: [B,H,S,D], coalesced float4 stores
        float* __restrict__ O = (which == 0) ? Q : V;
        #pragma unroll
        for (int i = 0; i < 4; ++i) {
            int s = (m0 & (S_ - 1)) + ty * 4 + i;
            int d = tx * 4;
            float4 r;
            r.x = c[i][0] + bias[n0 + d + 0];
            r.y = c[i][1] + bias[n0 + d + 1];
            r.z = c[i][2] + bias[n0 + d + 2];
            r.w = c[i][3] + bias[n0 + d + 3];
            *(float4*)&O[(((size_t)bb_ * H_ + hh) * S_ + s) * D_ + d] = r;
        }
    } else {
        // K: transpose in LDS, store [B,H,D,S] coalesced along s
        #pragma unroll
        for (int i = 0; i < 4; ++i)
            #pragma unroll
            for (int j = 0; j < 4; ++j)
                tbuf[tx * 4 + j][ty * 4 + i] = c[i][j] + bias[n0 + tx * 4 + j];
        __syncthreads();
        const int s0 = m0 & (S_ - 1);
        const int rn = tid >> 2;        // d index 0..63
        const int cm = (tid & 3) * 16;  // s sub-offset
        float* dst = &Kt[(((size_t)bb_ * H_ + hh) * D_ + rn) * S_ + s0 + cm];
        #pragma unroll
        for (int t = 0; t < 16; t += 4) {
            float4 r;
            r.x = tbuf[rn][cm + t + 0];
            r.y = tbuf[rn][cm + t + 1];
            r.z = tbuf[rn][cm + t + 2];
            r.w = tbuf[rn][cm + t + 3];
            *(float4*)&dst[t] = r;
        }
    }
}

// ---------------------------------------------------------------------------
// Kernel B: fused attention.  One wave (64 lanes) per (b,h,q) row.
//  - graph-relation score term is a 3-entry table lookup (t0=0, t1, t2)
//  - graph-relation value term is 2 bucket sums of probs times dp_v rows
//  - lane = k-column for scoring (8 cols/lane), lane = d for PV
// No __syncthreads needed: every wave touches only its own LDS slice.
// ---------------------------------------------------------------------------
__global__ __launch_bounds__(256) void attn_kernel(
    const float* __restrict__ Q,    // [B*H, S, D]
    const float* __restrict__ Kt,   // [B*H, D, S]
    const float* __restrict__ V,    // [B*H, S, D]
    const int*   __restrict__ ge,   // [B, S, S]
    const float* __restrict__ mask, // [B, S]
    const float* __restrict__ dpk,  // [3, D]
    const float* __restrict__ dpv,  // [3, D]
    float* __restrict__ out)        // [B, S, H*D]
{
    const int tid  = threadIdx.x;
    const int lane = tid & 63;
    const int wave = tid >> 6;
    const int g    = blockIdx.x * 4 + wave;   // (b*H + h)*S + qi
    const int bh   = g >> 9;
    const int qi   = g & (S_ - 1);
    const int b    = bh >> 4;
    const int h    = bh & (H_ - 1);

    __shared__ float q_lds[4][64];
    __shared__ float p_lds[4][520];

    // load q row (lane = d), stage in LDS for broadcast reads
    float qd = Q[(size_t)g * D_ + lane];
    q_lds[wave][lane] = qd;

    // t_r = q . dp_k[r]  (r=0 row is zeroed by the reference -> t0 = 0)
    float t1 = qd * dpk[1 * D_ + lane];
    float t2 = qd * dpk[2 * D_ + lane];
    #pragma unroll
    for (int off = 32; off > 0; off >>= 1) {
        t1 += __shfl_xor(t1, off);
        t2 += __shfl_xor(t2, off);
    }

    // scores: lane owns k = j*64 + lane, j = 0..7
    const float* ktb = Kt + (size_t)bh * D_ * S_ + lane;
    float acc[8] = {0, 0, 0, 0, 0, 0, 0, 0};
    for (int d = 0; d < D_; ++d) {
        float qv = q_lds[wave][d];
        const float* kr = ktb + (size_t)d * S_;
        #pragma unroll
        for (int j = 0; j < 8; ++j)
            acc[j] = fmaf(qv, kr[j * 64], acc[j]);
    }

    const int*   ger = ge + ((size_t)b * S_ + qi) * S_ + lane;
    const float* mr  = mask + (size_t)b * S_ + lane;
    float s[8];
    int   gc[8];
    #pragma unroll
    for (int j = 0; j < 8; ++j) {
        int code = ger[j * 64];
        float t  = (code == 1) ? t1 : (code == 2) ? t2 : 0.0f;
        s[j] = fmaf(acc[j], 0.125f, t + mr[j * 64]);
        gc[j] = code;
    }

    // two-pass softmax across the wave
    float mx = s[0];
    #pragma unroll
    for (int j = 1; j < 8; ++j) mx = fmaxf(mx, s[j]);
    #pragma unroll
    for (int off = 32; off > 0; off >>= 1) mx = fmaxf(mx, __shfl_xor(mx, off));

    float lsum = 0.f, w1 = 0.f, w2 = 0.f;
    float e[8];
    #pragma unroll
    for (int j = 0; j < 8; ++j) {
        e[j] = __expf(s[j] - mx);
        lsum += e[j];
        if (gc[j] == 1)      w1 += e[j];
        else if (gc[j] == 2) w2 += e[j];
    }
    #pragma unroll
    for (int off = 32; off > 0; off >>= 1) {
        lsum += __shfl_xor(lsum, off);
        w1   += __shfl_xor(w1, off);
        w2   += __shfl_xor(w2, off);
    }
    float inv = 1.0f / lsum;

    #pragma unroll
    for (int j = 0; j < 8; ++j)
        p_lds[wave][j * 64 + lane] = e[j] * inv;
    w1 *= inv;
    w2 *= inv;

    // PV: lane owns d = lane; p broadcast from LDS, V coalesced
    float ctx = 0.f;
    const float* vb = V + (size_t)bh * S_ * D_ + lane;
    for (int k = 0; k < S_; ++k)
        ctx = fmaf(p_lds[wave][k], vb[(size_t)k * D_], ctx);

    // relative-value term: w1*dp_v[1] + w2*dp_v[2]  (row 0 zeroed)
    ctx += w1 * dpv[1 * D_ + lane] + w2 * dpv[2 * D_ + lane];

    out[((size_t)b * S_ + qi) * (H_ * D_) + h * D_ + lane] = ctx;
}

extern "C" void kernel_launch(void* const* d_in, const int* in_sizes, int n_in,
                              void* d_out, int out_size, void* d_ws, size_t ws_size,
                              hipStream_t stream)
{
    const float* hs   = (const float*)d_in[0];
    const float* mask = (const float*)d_in[1];
    const int*   ge   = (const int*)d_in[2];
    const float* Wq   = (const float*)d_in[3];
    const float* bq   = (const float*)d_in[4];
    const float* Wk   = (const float*)d_in[5];
    const float* bk   = (const float*)d_in[6];
    const float* Wv   = (const float*)d_in[7];
    const float* bv   = (const float*)d_in[8];
    const float* dpk  = (const float*)d_in[9];
    const float* dpv  = (const float*)d_in[10];
    float* out = (float*)d_out;

    const size_t per = (size_t)B_ * H_ * S_ * D_;   // 4,194,304 floats
    float* ws = (float*)d_ws;
    float* Q  = ws;
    float* Kt = ws + per;
    float* V  = ws + 2 * per;

    dim3 gridA(HID / 64, (B_ * S_) / 64, 3);
    qkv_gemm_kernel<<<gridA, dim3(256), 0, stream>>>(hs, Wq, bq, Wk, bk, Wv, bv,
                                                     Q, Kt, V);

    dim3 gridB((B_ * H_ * S_) / 4);
    attn_kernel<<<gridB, dim3(256), 0, stream>>>(Q, Kt, V, ge, mask, dpk, dpv, out);
}

// Round 2
// 517.222 us; speedup vs baseline: 1.5671x; 1.5671x over previous
//
#include <hip/hip_runtime.h>
#include <hip/hip_bf16.h>
#include <cstddef>

#define B_  8
#define S_  512
#define HID 1024
#define H_  16
#define D_  64
#define QB  64
#define KB  64

// ---------------------------------------------------------------------------
// Kernel A: fused QKV projection.  Y = X @ W^T + b  for W in {Wq, Wk, Wv}
// (blockIdx.z selects which).  Q and V are written as [B,H,S,D]; K is written
// TRANSPOSED as [B,H,D,S] so the attention kernel can read K coalesced.
// ---------------------------------------------------------------------------
__global__ __launch_bounds__(256) void qkv_gemm_kernel(
    const float* __restrict__ X,
    const float* __restrict__ Wq, const float* __restrict__ bq,
    const float* __restrict__ Wk, const float* __restrict__ bk,
    const float* __restrict__ Wv, const float* __restrict__ bv,
    float* __restrict__ Q, float* __restrict__ Kt, float* __restrict__ V)
{
    const int which = blockIdx.z;
    const float* __restrict__ W    = (which == 0) ? Wq : (which == 1) ? Wk : Wv;
    const float* __restrict__ bias = (which == 0) ? bq : (which == 1) ? bk : bv;

    __shared__ float Xs[16][68];
    __shared__ float Ws[16][68];
    __shared__ float tbuf[64][65];

    const int tid  = threadIdx.x;
    const int tx   = tid & 15;
    const int ty   = tid >> 4;
    const int m0   = blockIdx.y * 64;
    const int n0   = blockIdx.x * 64;
    const int lrow = tid >> 2;
    const int lcol = (tid & 3) * 4;

    float c[4][4] = {};

    const float* xp = &X[(size_t)(m0 + lrow) * HID + lcol];
    const float* wp = &W[(size_t)(n0 + lrow) * HID + lcol];

    for (int k0 = 0; k0 < HID; k0 += 16) {
        float4 xv = *(const float4*)(xp + k0);
        float4 wv = *(const float4*)(wp + k0);
        __syncthreads();
        Xs[lcol + 0][lrow] = xv.x;
        Xs[lcol + 1][lrow] = xv.y;
        Xs[lcol + 2][lrow] = xv.z;
        Xs[lcol + 3][lrow] = xv.w;
        Ws[lcol + 0][lrow] = wv.x;
        Ws[lcol + 1][lrow] = wv.y;
        Ws[lcol + 2][lrow] = wv.z;
        Ws[lcol + 3][lrow] = wv.w;
        __syncthreads();
        #pragma unroll
        for (int kk = 0; kk < 16; ++kk) {
            float4 av  = *(const float4*)&Xs[kk][ty * 4];
            float4 bv4 = *(const float4*)&Ws[kk][tx * 4];
            float a[4]  = {av.x, av.y, av.z, av.w};
            float bb[4] = {bv4.x, bv4.y, bv4.z, bv4.w};
            #pragma unroll
            for (int i = 0; i < 4; ++i)
                #pragma unroll
                for (int j = 0; j < 4; ++j)
                    c[i][j] = fmaf(a[i], bb[j], c[i][j]);
        }
    }

    const int bb_ = m0 >> 9;
    const int hh  = n0 >> 6;

    if (which != 1) {
        float* __restrict__ O = (which == 0) ? Q : V;
        #pragma unroll
        for (int i = 0; i < 4; ++i) {
            int s = (m0 & (S_ - 1)) + ty * 4 + i;
            int d = tx * 4;
            float4 r;
            r.x = c[i][0] + bias[n0 + d + 0];
            r.y = c[i][1] + bias[n0 + d + 1];
            r.z = c[i][2] + bias[n0 + d + 2];
            r.w = c[i][3] + bias[n0 + d + 3];
            *(float4*)&O[(((size_t)bb_ * H_ + hh) * S_ + s) * D_ + d] = r;
        }
    } else {
        #pragma unroll
        for (int i = 0; i < 4; ++i)
            #pragma unroll
            for (int j = 0; j < 4; ++j)
                tbuf[tx * 4 + j][ty * 4 + i] = c[i][j] + bias[n0 + tx * 4 + j];
        __syncthreads();
        const int s0 = m0 & (S_ - 1);
        const int rn = tid >> 2;
        const int cm = (tid & 3) * 16;
        float* dst = &Kt[(((size_t)bb_ * H_ + hh) * D_ + rn) * S_ + s0 + cm];
        #pragma unroll
        for (int t = 0; t < 16; t += 4) {
            float4 r;
            r.x = tbuf[rn][cm + t + 0];
            r.y = tbuf[rn][cm + t + 1];
            r.z = tbuf[rn][cm + t + 2];
            r.w = tbuf[rn][cm + t + 3];
            *(float4*)&dst[t] = r;
        }
    }
}

// ---------------------------------------------------------------------------
// Kernel B: tiled flash-style attention.  One workgroup = one (b,h) x 64
// q-rows.  K/V staged in LDS per 64-wide k-tile and reused by all 64 rows
// (kills the 16.8 GB L2 re-read of the per-wave version).  Online softmax;
// 4x4 register microtile for both QK^T and PV.  Graph-relation score term =
// 3-entry lookup (t1/t2 per q-row); value term = 2 bucket sums (w1/w2),
// both rescaled by the online-softmax alpha.
// LDS: Qst + KsPt (K tile aliased with prob tile) + Vs  ~= 53 KB -> 3 wg/CU.
// ---------------------------------------------------------------------------
__global__ __launch_bounds__(256) void attn_tiled_kernel(
    const float* __restrict__ Q,    // [B*H, S, D]
    const float* __restrict__ Kt,   // [B*H, D, S]
    const float* __restrict__ V,    // [B*H, S, D]
    const int*   __restrict__ ge,   // [B, S, S]
    const float* __restrict__ mask, // [B, S]
    const float* __restrict__ dpk,  // [3, D]
    const float* __restrict__ dpv,  // [3, D]
    float* __restrict__ out)        // [B, S, H*D]
{
    __shared__ float Qst[D_][QB + 4];   // [d][q]
    __shared__ float KsPt[KB][KB + 4];  // Ks=[d][k] in score phase; Pt=[k][q] in PV
    __shared__ float Vs[KB][D_ + 4];    // [k][d]
    __shared__ float t1s[QB], t2s[QB];

    const int tid  = threadIdx.x;
    const int tx   = tid & 15;
    const int ty   = tid >> 4;
    const int lane = tid & 63;
    const int wv   = tid >> 6;
    const int bid  = blockIdx.x;
    const int bh   = bid >> 3;
    const int q0   = (bid & 7) * QB;
    const int b    = bh >> 4;
    const int h    = bh & (H_ - 1);

    // ---- prologue: stage Q transposed into LDS ----
    {
        const int q = tid >> 2, part = tid & 3;
        const float* src = &Q[((size_t)bh * S_ + q0 + q) * D_ + part * 16];
        #pragma unroll
        for (int u4 = 0; u4 < 4; ++u4) {
            float4 r = *(const float4*)(src + u4 * 4);
            Qst[part * 16 + u4 * 4 + 0][q] = r.x;
            Qst[part * 16 + u4 * 4 + 1][q] = r.y;
            Qst[part * 16 + u4 * 4 + 2][q] = r.z;
            Qst[part * 16 + u4 * 4 + 3][q] = r.w;
        }
    }
    // ---- t_r = q . dp_k[r]  (row 0 of dp_k is zeroed by reference) ----
    {
        const float d1 = dpk[D_ + lane];
        const float d2 = dpk[2 * D_ + lane];
        for (int r = 0; r < 16; ++r) {
            const int row = wv * 16 + r;
            const float qv = Q[((size_t)bh * S_ + q0 + row) * D_ + lane];
            float a1 = qv * d1, a2 = qv * d2;
            #pragma unroll
            for (int off = 32; off > 0; off >>= 1) {
                a1 += __shfl_xor(a1, off);
                a2 += __shfl_xor(a2, off);
            }
            if (lane == 0) { t1s[row] = a1; t2s[row] = a2; }
        }
    }

    float m[4], l[4], w1[4], w2[4];
    float ctx[4][4] = {};
    #pragma unroll
    for (int i = 0; i < 4; ++i) { m[i] = -INFINITY; l[i] = 0.f; w1[i] = 0.f; w2[i] = 0.f; }

    for (int kt = 0; kt < S_ / KB; ++kt) {
        const int k0 = kt * KB;

        // ---- stage K-tile [d][k] and V-tile [k][d] ----
        {
            const int r = tid >> 2, part = tid & 3;
            const float* ksrc = &Kt[((size_t)bh * D_ + r) * S_ + k0 + part * 16];
            const float* vsrc = &V[((size_t)bh * S_ + k0 + r) * D_ + part * 16];
            #pragma unroll
            for (int u = 0; u < 4; ++u) {
                *(float4*)&KsPt[r][part * 16 + u * 4] = *(const float4*)(ksrc + u * 4);
                *(float4*)&Vs[r][part * 16 + u * 4]   = *(const float4*)(vsrc + u * 4);
            }
        }
        __syncthreads();   // (1) tiles ready

        // ---- scores: sc[i][j] = q(ty*4+i) . k(tx*4+j) ----
        float sc[4][4] = {};
        #pragma unroll 8
        for (int d = 0; d < D_; ++d) {
            const float4 a  = *(const float4*)&Qst[d][ty * 4];
            const float4 kk = *(const float4*)&KsPt[d][tx * 4];
            const float aa[4] = {a.x, a.y, a.z, a.w};
            const float bb[4] = {kk.x, kk.y, kk.z, kk.w};
            #pragma unroll
            for (int i = 0; i < 4; ++i)
                #pragma unroll
                for (int j = 0; j < 4; ++j)
                    sc[i][j] = fmaf(aa[i], bb[j], sc[i][j]);
        }

        // ---- add relation lookup + mask; online softmax update ----
        const float4 mk = *(const float4*)&mask[(size_t)b * S_ + k0 + tx * 4];
        const float mka[4] = {mk.x, mk.y, mk.z, mk.w};
        int4 gc[4];
        #pragma unroll
        for (int i = 0; i < 4; ++i) {
            const int q = q0 + ty * 4 + i;
            gc[i] = *(const int4*)&ge[((size_t)b * S_ + q) * S_ + k0 + tx * 4];
            const float tt1 = t1s[ty * 4 + i];
            const float tt2 = t2s[ty * 4 + i];
            const int gg[4] = {gc[i].x, gc[i].y, gc[i].z, gc[i].w};
            #pragma unroll
            for (int j = 0; j < 4; ++j) {
                const float t = (gg[j] == 1) ? tt1 : (gg[j] == 2) ? tt2 : 0.f;
                sc[i][j] = fmaf(sc[i][j], 0.125f, t + mka[j]);
            }
        }

        #pragma unroll
        for (int i = 0; i < 4; ++i) {
            float tmax = fmaxf(fmaxf(sc[i][0], sc[i][1]), fmaxf(sc[i][2], sc[i][3]));
            tmax = fmaxf(tmax, __shfl_xor(tmax, 1));
            tmax = fmaxf(tmax, __shfl_xor(tmax, 2));
            tmax = fmaxf(tmax, __shfl_xor(tmax, 4));
            tmax = fmaxf(tmax, __shfl_xor(tmax, 8));
            const float mn    = fmaxf(m[i], tmax);
            const float alpha = __expf(m[i] - mn);
            m[i] = mn;
            const float e0 = __expf(sc[i][0] - mn);
            const float e1 = __expf(sc[i][1] - mn);
            const float e2 = __expf(sc[i][2] - mn);
            const float e3 = __expf(sc[i][3] - mn);
            float rs = e0 + e1 + e2 + e3;
            float b1 = (gc[i].x == 1 ? e0 : 0.f) + (gc[i].y == 1 ? e1 : 0.f)
                     + (gc[i].z == 1 ? e2 : 0.f) + (gc[i].w == 1 ? e3 : 0.f);
            float b2 = (gc[i].x == 2 ? e0 : 0.f) + (gc[i].y == 2 ? e1 : 0.f)
                     + (gc[i].z == 2 ? e2 : 0.f) + (gc[i].w == 2 ? e3 : 0.f);
            #pragma unroll
            for (int off = 8; off > 0; off >>= 1) {
                rs += __shfl_xor(rs, off);
                b1 += __shfl_xor(b1, off);
                b2 += __shfl_xor(b2, off);
            }
            l[i]  = l[i]  * alpha + rs;
            w1[i] = w1[i] * alpha + b1;
            w2[i] = w2[i] * alpha + b2;
            #pragma unroll
            for (int j = 0; j < 4; ++j) ctx[i][j] *= alpha;
            sc[i][0] = e0; sc[i][1] = e1; sc[i][2] = e2; sc[i][3] = e3;
        }
        __syncthreads();   // (2) all K-tile reads done before aliasing as Pt

        // ---- write probs transposed: Pt[k][q] ----
        #pragma unroll
        for (int i = 0; i < 4; ++i)
            #pragma unroll
            for (int j = 0; j < 4; ++j)
                KsPt[tx * 4 + j][ty * 4 + i] = sc[i][j];
        __syncthreads();   // (3) probs ready

        // ---- PV: ctx[q][d] += P[q][k] * V[k][d] ----
        #pragma unroll 8
        for (int k = 0; k < KB; ++k) {
            const float4 p  = *(const float4*)&KsPt[k][ty * 4];
            const float4 vv = *(const float4*)&Vs[k][tx * 4];
            const float pa[4] = {p.x, p.y, p.z, p.w};
            const float va[4] = {vv.x, vv.y, vv.z, vv.w};
            #pragma unroll
            for (int i = 0; i < 4; ++i)
                #pragma unroll
                for (int j = 0; j < 4; ++j)
                    ctx[i][j] = fmaf(pa[i], va[j], ctx[i][j]);
        }
        __syncthreads();   // (4) PV done before next tile overwrites LDS
    }

    // ---- epilogue: normalize, add relation-value term, store ----
    const float4 dv1 = *(const float4*)&dpv[D_ + tx * 4];
    const float4 dv2 = *(const float4*)&dpv[2 * D_ + tx * 4];
    #pragma unroll
    for (int i = 0; i < 4; ++i) {
        const float inv = 1.0f / l[i];
        float4 r;
        r.x = (ctx[i][0] + w1[i] * dv1.x + w2[i] * dv2.x) * inv;
        r.y = (ctx[i][1] + w1[i] * dv1.y + w2[i] * dv2.y) * inv;
        r.z = (ctx[i][2] + w1[i] * dv1.z + w2[i] * dv2.z) * inv;
        r.w = (ctx[i][3] + w1[i] * dv1.w + w2[i] * dv2.w) * inv;
        *(float4*)&out[((size_t)b * S_ + q0 + ty * 4 + i) * (H_ * D_) + h * D_ + tx * 4] = r;
    }
}

extern "C" void kernel_launch(void* const* d_in, const int* in_sizes, int n_in,
                              void* d_out, int out_size, void* d_ws, size_t ws_size,
                              hipStream_t stream)
{
    const float* hs   = (const float*)d_in[0];
    const float* mask = (const float*)d_in[1];
    const int*   ge   = (const int*)d_in[2];
    const float* Wq   = (const float*)d_in[3];
    const float* bq   = (const float*)d_in[4];
    const float* Wk   = (const float*)d_in[5];
    const float* bk   = (const float*)d_in[6];
    const float* Wv   = (const float*)d_in[7];
    const float* bv   = (const float*)d_in[8];
    const float* dpk  = (const float*)d_in[9];
    const float* dpv  = (const float*)d_in[10];
    float* out = (float*)d_out;

    const size_t per = (size_t)B_ * H_ * S_ * D_;
    float* ws = (float*)d_ws;
    float* Q  = ws;
    float* Kt = ws + per;
    float* V  = ws + 2 * per;

    dim3 gridA(HID / 64, (B_ * S_) / 64, 3);
    qkv_gemm_kernel<<<gridA, dim3(256), 0, stream>>>(hs, Wq, bq, Wk, bk, Wv, bv,
                                                     Q, Kt, V);

    dim3 gridB(B_ * H_ * (S_ / QB));
    attn_tiled_kernel<<<gridB, dim3(256), 0, stream>>>(Q, Kt, V, ge, mask, dpk, dpv, out);
}

// Round 3
// 282.265 us; speedup vs baseline: 2.8715x; 1.8324x over previous
//
#include <hip/hip_runtime.h>
#include <hip/hip_bf16.h>
#include <cstddef>

#define B_  8
#define S_  512
#define HID 1024
#define H_  16
#define D_  64
#define QB  64
#define KB  64

typedef float f32x4 __attribute__((ext_vector_type(4)));
typedef short s16x8 __attribute__((ext_vector_type(8)));
typedef unsigned short ushort_t;

// slot swizzle for 64B rows of 4x16B slots: keeps ds_write_b128 and
// ds_read_b128 (MFMA fragment reads) at <=2-way bank conflicts (free, m136)
#define SWZ4(r) (((r) >> 1) & 3)

// ---------------------------------------------------------------------------
// conv_split: f32 -> bf16 hi + bf16 residual-lo  (RN-even via bit math).
// x = hi + lo + O(2^-18 * x)
// ---------------------------------------------------------------------------
__device__ __forceinline__ void split1(float v, ushort_t& h, ushort_t& l) {
    unsigned u = __builtin_bit_cast(unsigned, v);
    unsigned hb = (u + 0x7FFFu + ((u >> 16) & 1u)) & 0xFFFF0000u;
    h = (ushort_t)(hb >> 16);
    float r = v - __builtin_bit_cast(float, hb);
    unsigned ur = __builtin_bit_cast(unsigned, r);
    unsigned lb = (ur + 0x7FFFu + ((ur >> 16) & 1u)) & 0xFFFF0000u;
    l = (ushort_t)(lb >> 16);
}

__global__ __launch_bounds__(256) void conv_split_kernel(
    const float* __restrict__ src, ushort_t* __restrict__ hi,
    ushort_t* __restrict__ lo, int n4)
{
    int i = blockIdx.x * 256 + threadIdx.x;
    if (i >= n4) return;
    float4 x = ((const float4*)src)[i];
    ushort4 h, l;
    split1(x.x, h.x, l.x);
    split1(x.y, h.y, l.y);
    split1(x.z, h.z, l.z);
    split1(x.w, h.w, l.w);
    ((ushort4*)hi)[i] = h;
    ((ushort4*)lo)[i] = l;
}

// ---------------------------------------------------------------------------
// Kernel A (fast path): QKV projection via bf16 MFMA, 3-term split:
//   Y = Xhi@Whi^T + Xlo@Whi^T + Xhi@Wlo^T  (+bias), error ~2^-18 rel.
// 128x128 tile, BK=32, 4 waves each owning a 64x64 subtile (4x4 frags of
// mfma_f32_16x16x32_bf16).  Q,V stored [B,H,S,D]; K stored [B,H,D,S].
// ---------------------------------------------------------------------------
__global__ __launch_bounds__(256) void qkv_mfma_kernel(
    const ushort_t* __restrict__ Xhi, const ushort_t* __restrict__ Xlo,
    const ushort_t* __restrict__ Whi, const ushort_t* __restrict__ Wlo,
    const float* __restrict__ bq, const float* __restrict__ bk,
    const float* __restrict__ bv,
    float* __restrict__ Q, float* __restrict__ Kt, float* __restrict__ V)
{
    const int which = blockIdx.z;
    const ushort_t* __restrict__ WhiB = Whi + (size_t)which * (HID * HID);
    const ushort_t* __restrict__ WloB = Wlo + (size_t)which * (HID * HID);
    const float*  __restrict__ bias = (which == 0) ? bq : (which == 1) ? bk : bv;

    __shared__ __align__(16) ushort_t Ah[128 * 32];
    __shared__ __align__(16) ushort_t Al[128 * 32];
    __shared__ __align__(16) ushort_t Bh[128 * 32];
    __shared__ __align__(16) ushort_t Bl[128 * 32];

    const int tid  = threadIdx.x;
    const int lane = tid & 63;
    const int wv_  = tid >> 6;
    const int wr   = wv_ >> 1;
    const int wc   = wv_ & 1;
    const int m0   = blockIdx.y * 128;
    const int n0   = blockIdx.x * 128;

    f32x4 acc[4][4];
    #pragma unroll
    for (int mi = 0; mi < 4; ++mi)
        #pragma unroll
        for (int ni = 0; ni < 4; ++ni)
            #pragma unroll
            for (int e = 0; e < 4; ++e) acc[mi][ni][e] = 0.0f;

    // staging: thread owns 16B chunks c and c+256 of each 8KB tile
    const int r0  = tid >> 2;          // row 0..63
    const int sc  = tid & 3;           // slot
    const int lds0 = r0 * 32 + ((sc ^ SWZ4(r0)) << 3);   // ushort units
    const int lds1 = lds0 + 64 * 32;                     // row+64, same swizzle
    const size_t aoff0 = (size_t)(m0 + r0) * HID + sc * 8;
    const size_t aoff1 = aoff0 + (size_t)64 * HID;
    const size_t boff0 = (size_t)(n0 + r0) * HID + sc * 8;
    const size_t boff1 = boff0 + (size_t)64 * HID;

    // fragment read bases
    const int colL = lane & 15;
    const int kg   = lane >> 4;
    const int fswz = kg ^ SWZ4(colL);
    const int abase = (wr * 64 + colL) * 32 + fswz * 8;
    const int bbase = (wc * 64 + colL) * 32 + fswz * 8;

    for (int k0 = 0; k0 < HID; k0 += 32) {
        s16x8 vah0 = *(const s16x8*)&Xhi [aoff0 + k0];
        s16x8 vah1 = *(const s16x8*)&Xhi [aoff1 + k0];
        s16x8 val0 = *(const s16x8*)&Xlo [aoff0 + k0];
        s16x8 val1 = *(const s16x8*)&Xlo [aoff1 + k0];
        s16x8 vbh0 = *(const s16x8*)&WhiB[boff0 + k0];
        s16x8 vbh1 = *(const s16x8*)&WhiB[boff1 + k0];
        s16x8 vbl0 = *(const s16x8*)&WloB[boff0 + k0];
        s16x8 vbl1 = *(const s16x8*)&WloB[boff1 + k0];

        __syncthreads();   // prior iteration's fragment reads complete
        *(s16x8*)&Ah[lds0] = vah0;  *(s16x8*)&Ah[lds1] = vah1;
        *(s16x8*)&Al[lds0] = val0;  *(s16x8*)&Al[lds1] = val1;
        *(s16x8*)&Bh[lds0] = vbh0;  *(s16x8*)&Bh[lds1] = vbh1;
        *(s16x8*)&Bl[lds0] = vbl0;  *(s16x8*)&Bl[lds1] = vbl1;
        __syncthreads();   // tiles ready

        s16x8 ah[4], fb[4], t4[4];
        #pragma unroll
        for (int mi = 0; mi < 4; ++mi)
            ah[mi] = *(const s16x8*)&Ah[abase + mi * 512];
        #pragma unroll
        for (int ni = 0; ni < 4; ++ni)
            fb[ni] = *(const s16x8*)&Bh[bbase + ni * 512];
        #pragma unroll
        for (int mi = 0; mi < 4; ++mi)
            #pragma unroll
            for (int ni = 0; ni < 4; ++ni)
                acc[mi][ni] = __builtin_amdgcn_mfma_f32_16x16x32_bf16(
                    ah[mi], fb[ni], acc[mi][ni], 0, 0, 0);

        #pragma unroll
        for (int mi = 0; mi < 4; ++mi)
            t4[mi] = *(const s16x8*)&Al[abase + mi * 512];
        #pragma unroll
        for (int mi = 0; mi < 4; ++mi)
            #pragma unroll
            for (int ni = 0; ni < 4; ++ni)
                acc[mi][ni] = __builtin_amdgcn_mfma_f32_16x16x32_bf16(
                    t4[mi], fb[ni], acc[mi][ni], 0, 0, 0);

        #pragma unroll
        for (int ni = 0; ni < 4; ++ni)
            t4[ni] = *(const s16x8*)&Bl[bbase + ni * 512];
        #pragma unroll
        for (int mi = 0; mi < 4; ++mi)
            #pragma unroll
            for (int ni = 0; ni < 4; ++ni)
                acc[mi][ni] = __builtin_amdgcn_mfma_f32_16x16x32_bf16(
                    ah[mi], t4[ni], acc[mi][ni], 0, 0, 0);
    }

    // epilogue.  C/D layout: col = lane&15, row = (lane>>4)*4 + reg.
    #pragma unroll
    for (int mi = 0; mi < 4; ++mi) {
        #pragma unroll
        for (int ni = 0; ni < 4; ++ni) {
            const int n    = n0 + wc * 64 + ni * 16 + colL;
            const int mrow = m0 + wr * 64 + mi * 16 + kg * 4;
            const float bn = bias[n];
            const int bb = mrow >> 9;
            const int ss = mrow & (S_ - 1);
            const int hh = n >> 6;
            const int dd = n & (D_ - 1);
            if (which == 1) {
                float4 rv;
                rv.x = acc[mi][ni][0] + bn;
                rv.y = acc[mi][ni][1] + bn;
                rv.z = acc[mi][ni][2] + bn;
                rv.w = acc[mi][ni][3] + bn;
                *(float4*)&Kt[(((size_t)bb * H_ + hh) * D_ + dd) * S_ + ss] = rv;
            } else {
                float* __restrict__ O = (which == 0) ? Q : V;
                #pragma unroll
                for (int j = 0; j < 4; ++j)
                    O[(((size_t)bb * H_ + hh) * S_ + ss + j) * D_ + dd] =
                        acc[mi][ni][j] + bn;
            }
        }
    }
}

// ---------------------------------------------------------------------------
// Kernel A (fallback if workspace too small): f32 vector GEMM (round-2 ver.)
// ---------------------------------------------------------------------------
__global__ __launch_bounds__(256) void qkv_gemm_kernel(
    const float* __restrict__ X,
    const float* __restrict__ Wq, const float* __restrict__ bq,
    const float* __restrict__ Wk, const float* __restrict__ bk,
    const float* __restrict__ Wv, const float* __restrict__ bv,
    float* __restrict__ Q, float* __restrict__ Kt, float* __restrict__ V)
{
    const int which = blockIdx.z;
    const float* __restrict__ W    = (which == 0) ? Wq : (which == 1) ? Wk : Wv;
    const float* __restrict__ bias = (which == 0) ? bq : (which == 1) ? bk : bv;

    __shared__ float Xs[16][68];
    __shared__ float Ws[16][68];
    __shared__ float tbuf[64][65];

    const int tid  = threadIdx.x;
    const int tx   = tid & 15;
    const int ty   = tid >> 4;
    const int m0   = blockIdx.y * 64;
    const int n0   = blockIdx.x * 64;
    const int lrow = tid >> 2;
    const int lcol = (tid & 3) * 4;

    float c[4][4] = {};
    const float* xp = &X[(size_t)(m0 + lrow) * HID + lcol];
    const float* wp = &W[(size_t)(n0 + lrow) * HID + lcol];

    for (int k0 = 0; k0 < HID; k0 += 16) {
        float4 xv = *(const float4*)(xp + k0);
        float4 wv = *(const float4*)(wp + k0);
        __syncthreads();
        Xs[lcol + 0][lrow] = xv.x; Xs[lcol + 1][lrow] = xv.y;
        Xs[lcol + 2][lrow] = xv.z; Xs[lcol + 3][lrow] = xv.w;
        Ws[lcol + 0][lrow] = wv.x; Ws[lcol + 1][lrow] = wv.y;
        Ws[lcol + 2][lrow] = wv.z; Ws[lcol + 3][lrow] = wv.w;
        __syncthreads();
        #pragma unroll
        for (int kk = 0; kk < 16; ++kk) {
            float4 av  = *(const float4*)&Xs[kk][ty * 4];
            float4 bv4 = *(const float4*)&Ws[kk][tx * 4];
            float a[4]  = {av.x, av.y, av.z, av.w};
            float bb[4] = {bv4.x, bv4.y, bv4.z, bv4.w};
            #pragma unroll
            for (int i = 0; i < 4; ++i)
                #pragma unroll
                for (int j = 0; j < 4; ++j)
                    c[i][j] = fmaf(a[i], bb[j], c[i][j]);
        }
    }

    const int bb_ = m0 >> 9;
    const int hh  = n0 >> 6;

    if (which != 1) {
        float* __restrict__ O = (which == 0) ? Q : V;
        #pragma unroll
        for (int i = 0; i < 4; ++i) {
            int s = (m0 & (S_ - 1)) + ty * 4 + i;
            int d = tx * 4;
            float4 r;
            r.x = c[i][0] + bias[n0 + d + 0];
            r.y = c[i][1] + bias[n0 + d + 1];
            r.z = c[i][2] + bias[n0 + d + 2];
            r.w = c[i][3] + bias[n0 + d + 3];
            *(float4*)&O[(((size_t)bb_ * H_ + hh) * S_ + s) * D_ + d] = r;
        }
    } else {
        #pragma unroll
        for (int i = 0; i < 4; ++i)
            #pragma unroll
            for (int j = 0; j < 4; ++j)
                tbuf[tx * 4 + j][ty * 4 + i] = c[i][j] + bias[n0 + tx * 4 + j];
        __syncthreads();
        const int s0 = m0 & (S_ - 1);
        const int rn = tid >> 2;
        const int cm = (tid & 3) * 16;
        float* dst = &Kt[(((size_t)bb_ * H_ + hh) * D_ + rn) * S_ + s0 + cm];
        #pragma unroll
        for (int t = 0; t < 16; t += 4) {
            float4 r;
            r.x = tbuf[rn][cm + t + 0]; r.y = tbuf[rn][cm + t + 1];
            r.z = tbuf[rn][cm + t + 2]; r.w = tbuf[rn][cm + t + 3];
            *(float4*)&dst[t] = r;
        }
    }
}

// ---------------------------------------------------------------------------
// Kernel B: tiled flash-style attention (unchanged from round 2).
// ---------------------------------------------------------------------------
__global__ __launch_bounds__(256) void attn_tiled_kernel(
    const float* __restrict__ Q, const float* __restrict__ Kt,
    const float* __restrict__ V, const int* __restrict__ ge,
    const float* __restrict__ mask, const float* __restrict__ dpk,
    const float* __restrict__ dpv, float* __restrict__ out)
{
    __shared__ float Qst[D_][QB + 4];
    __shared__ float KsPt[KB][KB + 4];
    __shared__ float Vs[KB][D_ + 4];
    __shared__ float t1s[QB], t2s[QB];

    const int tid  = threadIdx.x;
    const int tx   = tid & 15;
    const int ty   = tid >> 4;
    const int lane = tid & 63;
    const int wv   = tid >> 6;
    const int bid  = blockIdx.x;
    const int bh   = bid >> 3;
    const int q0   = (bid & 7) * QB;
    const int b    = bh >> 4;
    const int h    = bh & (H_ - 1);

    {
        const int q = tid >> 2, part = tid & 3;
        const float* src = &Q[((size_t)bh * S_ + q0 + q) * D_ + part * 16];
        #pragma unroll
        for (int u4 = 0; u4 < 4; ++u4) {
            float4 r = *(const float4*)(src + u4 * 4);
            Qst[part * 16 + u4 * 4 + 0][q] = r.x;
            Qst[part * 16 + u4 * 4 + 1][q] = r.y;
            Qst[part * 16 + u4 * 4 + 2][q] = r.z;
            Qst[part * 16 + u4 * 4 + 3][q] = r.w;
        }
    }
    {
        const float d1 = dpk[D_ + lane];
        const float d2 = dpk[2 * D_ + lane];
        for (int r = 0; r < 16; ++r) {
            const int row = wv * 16 + r;
            const float qv = Q[((size_t)bh * S_ + q0 + row) * D_ + lane];
            float a1 = qv * d1, a2 = qv * d2;
            #pragma unroll
            for (int off = 32; off > 0; off >>= 1) {
                a1 += __shfl_xor(a1, off);
                a2 += __shfl_xor(a2, off);
            }
            if (lane == 0) { t1s[row] = a1; t2s[row] = a2; }
        }
    }

    float m[4], l[4], w1[4], w2[4];
    float ctx[4][4] = {};
    #pragma unroll
    for (int i = 0; i < 4; ++i) { m[i] = -INFINITY; l[i] = 0.f; w1[i] = 0.f; w2[i] = 0.f; }

    for (int kt = 0; kt < S_ / KB; ++kt) {
        const int k0 = kt * KB;
        {
            const int r = tid >> 2, part = tid & 3;
            const float* ksrc = &Kt[((size_t)bh * D_ + r) * S_ + k0 + part * 16];
            const float* vsrc = &V[((size_t)bh * S_ + k0 + r) * D_ + part * 16];
            #pragma unroll
            for (int u = 0; u < 4; ++u) {
                *(float4*)&KsPt[r][part * 16 + u * 4] = *(const float4*)(ksrc + u * 4);
                *(float4*)&Vs[r][part * 16 + u * 4]   = *(const float4*)(vsrc + u * 4);
            }
        }
        __syncthreads();

        float sc[4][4] = {};
        #pragma unroll 8
        for (int d = 0; d < D_; ++d) {
            const float4 a  = *(const float4*)&Qst[d][ty * 4];
            const float4 kk = *(const float4*)&KsPt[d][tx * 4];
            const float aa[4] = {a.x, a.y, a.z, a.w};
            const float bb[4] = {kk.x, kk.y, kk.z, kk.w};
            #pragma unroll
            for (int i = 0; i < 4; ++i)
                #pragma unroll
                for (int j = 0; j < 4; ++j)
                    sc[i][j] = fmaf(aa[i], bb[j], sc[i][j]);
        }

        const float4 mk = *(const float4*)&mask[(size_t)b * S_ + k0 + tx * 4];
        const float mka[4] = {mk.x, mk.y, mk.z, mk.w};
        int4 gc[4];
        #pragma unroll
        for (int i = 0; i < 4; ++i) {
            const int q = q0 + ty * 4 + i;
            gc[i] = *(const int4*)&ge[((size_t)b * S_ + q) * S_ + k0 + tx * 4];
            const float tt1 = t1s[ty * 4 + i];
            const float tt2 = t2s[ty * 4 + i];
            const int gg[4] = {gc[i].x, gc[i].y, gc[i].z, gc[i].w};
            #pragma unroll
            for (int j = 0; j < 4; ++j) {
                const float t = (gg[j] == 1) ? tt1 : (gg[j] == 2) ? tt2 : 0.f;
                sc[i][j] = fmaf(sc[i][j], 0.125f, t + mka[j]);
            }
        }

        #pragma unroll
        for (int i = 0; i < 4; ++i) {
            float tmax = fmaxf(fmaxf(sc[i][0], sc[i][1]), fmaxf(sc[i][2], sc[i][3]));
            tmax = fmaxf(tmax, __shfl_xor(tmax, 1));
            tmax = fmaxf(tmax, __shfl_xor(tmax, 2));
            tmax = fmaxf(tmax, __shfl_xor(tmax, 4));
            tmax = fmaxf(tmax, __shfl_xor(tmax, 8));
            const float mn    = fmaxf(m[i], tmax);
            const float alpha = __expf(m[i] - mn);
            m[i] = mn;
            const float e0 = __expf(sc[i][0] - mn);
            const float e1 = __expf(sc[i][1] - mn);
            const float e2 = __expf(sc[i][2] - mn);
            const float e3 = __expf(sc[i][3] - mn);
            float rs = e0 + e1 + e2 + e3;
            float b1 = (gc[i].x == 1 ? e0 : 0.f) + (gc[i].y == 1 ? e1 : 0.f)
                     + (gc[i].z == 1 ? e2 : 0.f) + (gc[i].w == 1 ? e3 : 0.f);
            float b2 = (gc[i].x == 2 ? e0 : 0.f) + (gc[i].y == 2 ? e1 : 0.f)
                     + (gc[i].z == 2 ? e2 : 0.f) + (gc[i].w == 2 ? e3 : 0.f);
            #pragma unroll
            for (int off = 8; off > 0; off >>= 1) {
                rs += __shfl_xor(rs, off);
                b1 += __shfl_xor(b1, off);
                b2 += __shfl_xor(b2, off);
            }
            l[i]  = l[i]  * alpha + rs;
            w1[i] = w1[i] * alpha + b1;
            w2[i] = w2[i] * alpha + b2;
            #pragma unroll
            for (int j = 0; j < 4; ++j) ctx[i][j] *= alpha;
            sc[i][0] = e0; sc[i][1] = e1; sc[i][2] = e2; sc[i][3] = e3;
        }
        __syncthreads();

        #pragma unroll
        for (int i = 0; i < 4; ++i)
            #pragma unroll
            for (int j = 0; j < 4; ++j)
                KsPt[tx * 4 + j][ty * 4 + i] = sc[i][j];
        __syncthreads();

        #pragma unroll 8
        for (int k = 0; k < KB; ++k) {
            const float4 p  = *(const float4*)&KsPt[k][ty * 4];
            const float4 vv = *(const float4*)&Vs[k][tx * 4];
            const float pa[4] = {p.x, p.y, p.z, p.w};
            const float va[4] = {vv.x, vv.y, vv.z, vv.w};
            #pragma unroll
            for (int i = 0; i < 4; ++i)
                #pragma unroll
                for (int j = 0; j < 4; ++j)
                    ctx[i][j] = fmaf(pa[i], va[j], ctx[i][j]);
        }
        __syncthreads();
    }

    const float4 dv1 = *(const float4*)&dpv[D_ + tx * 4];
    const float4 dv2 = *(const float4*)&dpv[2 * D_ + tx * 4];
    #pragma unroll
    for (int i = 0; i < 4; ++i) {
        const float inv = 1.0f / l[i];
        float4 r;
        r.x = (ctx[i][0] + w1[i] * dv1.x + w2[i] * dv2.x) * inv;
        r.y = (ctx[i][1] + w1[i] * dv1.y + w2[i] * dv2.y) * inv;
        r.z = (ctx[i][2] + w1[i] * dv1.z + w2[i] * dv2.z) * inv;
        r.w = (ctx[i][3] + w1[i] * dv1.w + w2[i] * dv2.w) * inv;
        *(float4*)&out[((size_t)b * S_ + q0 + ty * 4 + i) * (H_ * D_) + h * D_ + tx * 4] = r;
    }
}

extern "C" void kernel_launch(void* const* d_in, const int* in_sizes, int n_in,
                              void* d_out, int out_size, void* d_ws, size_t ws_size,
                              hipStream_t stream)
{
    const float* hs   = (const float*)d_in[0];
    const float* mask = (const float*)d_in[1];
    const int*   ge   = (const int*)d_in[2];
    const float* Wq   = (const float*)d_in[3];
    const float* bq   = (const float*)d_in[4];
    const float* Wk   = (const float*)d_in[5];
    const float* bk   = (const float*)d_in[6];
    const float* Wv   = (const float*)d_in[7];
    const float* bv   = (const float*)d_in[8];
    const float* dpk  = (const float*)d_in[9];
    const float* dpv  = (const float*)d_in[10];
    float* out = (float*)d_out;

    const size_t per = (size_t)B_ * H_ * S_ * D_;     // 4,194,304 floats
    float* ws = (float*)d_ws;
    float* Q  = ws;
    float* Kt = ws + per;
    float* V  = ws + 2 * per;

    const size_t nX = (size_t)B_ * S_ * HID;          // 4,194,304
    const size_t nW = (size_t)HID * HID;              // 1,048,576
    const size_t needed = 3 * per * sizeof(float) + (2 * nX + 2 * 3 * nW) * sizeof(ushort_t);

    if (ws_size >= needed) {
        ushort_t* b16 = (ushort_t*)(ws + 3 * per);
        ushort_t* Xhi = b16;
        ushort_t* Xlo = Xhi + nX;
        ushort_t* Whi = Xlo + nX;
        ushort_t* Wlo = Whi + 3 * nW;

        conv_split_kernel<<<(int)(nX / 4 / 256), 256, 0, stream>>>(hs, Xhi, Xlo, (int)(nX / 4));
        conv_split_kernel<<<(int)(nW / 4 / 256), 256, 0, stream>>>(Wq, Whi,          Wlo,          (int)(nW / 4));
        conv_split_kernel<<<(int)(nW / 4 / 256), 256, 0, stream>>>(Wk, Whi + nW,     Wlo + nW,     (int)(nW / 4));
        conv_split_kernel<<<(int)(nW / 4 / 256), 256, 0, stream>>>(Wv, Whi + 2 * nW, Wlo + 2 * nW, (int)(nW / 4));

        dim3 gridG(HID / 128, (B_ * S_) / 128, 3);
        qkv_mfma_kernel<<<gridG, dim3(256), 0, stream>>>(
            Xhi, Xlo, Whi, Wlo, bq, bk, bv, Q, Kt, V);
    } else {
        dim3 gridA(HID / 64, (B_ * S_) / 64, 3);
        qkv_gemm_kernel<<<gridA, dim3(256), 0, stream>>>(hs, Wq, bq, Wk, bk, Wv, bv,
                                                         Q, Kt, V);
    }

    dim3 gridB(B_ * H_ * (S_ / QB));
    attn_tiled_kernel<<<gridB, dim3(256), 0, stream>>>(Q, Kt, V, ge, mask, dpk, dpv, out);
}

// Round 4
// 193.122 us; speedup vs baseline: 4.1969x; 1.4616x over previous
//
#include <hip/hip_runtime.h>
#include <hip/hip_bf16.h>
#include <cstddef>

#define B_  8
#define S_  512
#define HID 1024
#define H_  16
#define D_  64

typedef float f32x4 __attribute__((ext_vector_type(4)));
typedef short s16x8 __attribute__((ext_vector_type(8)));
typedef unsigned short u16t;

#define SWZ4(r) (((r) >> 1) & 3)

__device__ __forceinline__ float b2f(u16t u) {
    return __builtin_bit_cast(float, ((unsigned)u) << 16);
}

// f32 -> bf16 hi + bf16 residual lo (both RNE).  x = hi + lo + O(2^-18 x)
__device__ __forceinline__ void split1(float v, u16t& h, u16t& l) {
    unsigned u = __builtin_bit_cast(unsigned, v);
    unsigned hb = (u + 0x7FFFu + ((u >> 16) & 1u)) & 0xFFFF0000u;
    h = (u16t)(hb >> 16);
    float r = v - __builtin_bit_cast(float, hb);
    unsigned ur = __builtin_bit_cast(unsigned, r);
    unsigned lb = (ur + 0x7FFFu + ((ur >> 16) & 1u)) & 0xFFFF0000u;
    l = (u16t)(lb >> 16);
}

__global__ __launch_bounds__(256) void conv_split_kernel(
    const float* __restrict__ src, u16t* __restrict__ hi,
    u16t* __restrict__ lo, int n4)
{
    int i = blockIdx.x * 256 + threadIdx.x;
    if (i >= n4) return;
    float4 x = ((const float4*)src)[i];
    ushort4 h, l;
    split1(x.x, h.x, l.x);
    split1(x.y, h.y, l.y);
    split1(x.z, h.z, l.z);
    split1(x.w, h.w, l.w);
    ((ushort4*)hi)[i] = h;
    ((ushort4*)lo)[i] = l;
}

// ---------------------------------------------------------------------------
// QKV projection via bf16-split MFMA.  Outputs bf16 hi/lo directly:
//   which=0 -> Qhi/Qlo [B,H,S,D];  which=1 -> Khi/Klo [B,H,S,D];
//   which=2 -> Vthi/Vtlo [B,H,D,S] (transposed for the PV A-operand).
// ---------------------------------------------------------------------------
__global__ __launch_bounds__(256) void qkv_mfma_kernel(
    const u16t* __restrict__ Xhi, const u16t* __restrict__ Xlo,
    const u16t* __restrict__ Whi, const u16t* __restrict__ Wlo,
    const float* __restrict__ bq, const float* __restrict__ bk,
    const float* __restrict__ bv,
    u16t* __restrict__ Qh, u16t* __restrict__ Ql,
    u16t* __restrict__ Kh, u16t* __restrict__ Kl,
    u16t* __restrict__ Vth, u16t* __restrict__ Vtl)
{
    const int which = blockIdx.z;
    const u16t* __restrict__ WhiB = Whi + (size_t)which * (HID * HID);
    const u16t* __restrict__ WloB = Wlo + (size_t)which * (HID * HID);
    const float* __restrict__ bias = (which == 0) ? bq : (which == 1) ? bk : bv;

    __shared__ __align__(16) u16t Ah[128 * 32];
    __shared__ __align__(16) u16t Al[128 * 32];
    __shared__ __align__(16) u16t Bh[128 * 32];
    __shared__ __align__(16) u16t Bl[128 * 32];

    const int tid  = threadIdx.x;
    const int lane = tid & 63;
    const int wv_  = tid >> 6;
    const int wr   = wv_ >> 1;
    const int wc   = wv_ & 1;
    const int m0   = blockIdx.y * 128;
    const int n0   = blockIdx.x * 128;

    f32x4 acc[4][4];
    #pragma unroll
    for (int mi = 0; mi < 4; ++mi)
        #pragma unroll
        for (int ni = 0; ni < 4; ++ni)
            #pragma unroll
            for (int e = 0; e < 4; ++e) acc[mi][ni][e] = 0.0f;

    const int r0  = tid >> 2;
    const int sc_ = tid & 3;
    const int lds0 = r0 * 32 + ((sc_ ^ SWZ4(r0)) << 3);
    const int lds1 = lds0 + 64 * 32;
    const size_t aoff0 = (size_t)(m0 + r0) * HID + sc_ * 8;
    const size_t aoff1 = aoff0 + (size_t)64 * HID;
    const size_t boff0 = (size_t)(n0 + r0) * HID + sc_ * 8;
    const size_t boff1 = boff0 + (size_t)64 * HID;

    const int colL = lane & 15;
    const int kg   = lane >> 4;
    const int fswz = kg ^ SWZ4(colL);
    const int abase = (wr * 64 + colL) * 32 + fswz * 8;
    const int bbase = (wc * 64 + colL) * 32 + fswz * 8;

    for (int k0 = 0; k0 < HID; k0 += 32) {
        s16x8 vah0 = *(const s16x8*)&Xhi [aoff0 + k0];
        s16x8 vah1 = *(const s16x8*)&Xhi [aoff1 + k0];
        s16x8 val0 = *(const s16x8*)&Xlo [aoff0 + k0];
        s16x8 val1 = *(const s16x8*)&Xlo [aoff1 + k0];
        s16x8 vbh0 = *(const s16x8*)&WhiB[boff0 + k0];
        s16x8 vbh1 = *(const s16x8*)&WhiB[boff1 + k0];
        s16x8 vbl0 = *(const s16x8*)&WloB[boff0 + k0];
        s16x8 vbl1 = *(const s16x8*)&WloB[boff1 + k0];

        __syncthreads();
        *(s16x8*)&Ah[lds0] = vah0;  *(s16x8*)&Ah[lds1] = vah1;
        *(s16x8*)&Al[lds0] = val0;  *(s16x8*)&Al[lds1] = val1;
        *(s16x8*)&Bh[lds0] = vbh0;  *(s16x8*)&Bh[lds1] = vbh1;
        *(s16x8*)&Bl[lds0] = vbl0;  *(s16x8*)&Bl[lds1] = vbl1;
        __syncthreads();

        s16x8 ah[4], fb[4], t4[4];
        #pragma unroll
        for (int mi = 0; mi < 4; ++mi)
            ah[mi] = *(const s16x8*)&Ah[abase + mi * 512];
        #pragma unroll
        for (int ni = 0; ni < 4; ++ni)
            fb[ni] = *(const s16x8*)&Bh[bbase + ni * 512];
        #pragma unroll
        for (int mi = 0; mi < 4; ++mi)
            #pragma unroll
            for (int ni = 0; ni < 4; ++ni)
                acc[mi][ni] = __builtin_amdgcn_mfma_f32_16x16x32_bf16(
                    ah[mi], fb[ni], acc[mi][ni], 0, 0, 0);

        #pragma unroll
        for (int mi = 0; mi < 4; ++mi)
            t4[mi] = *(const s16x8*)&Al[abase + mi * 512];
        #pragma unroll
        for (int mi = 0; mi < 4; ++mi)
            #pragma unroll
            for (int ni = 0; ni < 4; ++ni)
                acc[mi][ni] = __builtin_amdgcn_mfma_f32_16x16x32_bf16(
                    t4[mi], fb[ni], acc[mi][ni], 0, 0, 0);

        #pragma unroll
        for (int ni = 0; ni < 4; ++ni)
            t4[ni] = *(const s16x8*)&Bl[bbase + ni * 512];
        #pragma unroll
        for (int mi = 0; mi < 4; ++mi)
            #pragma unroll
            for (int ni = 0; ni < 4; ++ni)
                acc[mi][ni] = __builtin_amdgcn_mfma_f32_16x16x32_bf16(
                    ah[mi], t4[ni], acc[mi][ni], 0, 0, 0);
    }

    // epilogue: C/D layout col=lane&15, row=(lane>>4)*4+reg
    #pragma unroll
    for (int mi = 0; mi < 4; ++mi) {
        #pragma unroll
        for (int ni = 0; ni < 4; ++ni) {
            const int n    = n0 + wc * 64 + ni * 16 + colL;
            const int mrow = m0 + wr * 64 + mi * 16 + kg * 4;
            const float bn = bias[n];
            const int bb = mrow >> 9;
            const int ss = mrow & (S_ - 1);
            const int hh = n >> 6;
            const int dd = n & (D_ - 1);
            if (which == 2) {
                ushort4 vh, vl;
                u16t h0, l0;
                split1(acc[mi][ni][0] + bn, h0, l0); vh.x = h0; vl.x = l0;
                split1(acc[mi][ni][1] + bn, h0, l0); vh.y = h0; vl.y = l0;
                split1(acc[mi][ni][2] + bn, h0, l0); vh.z = h0; vl.z = l0;
                split1(acc[mi][ni][3] + bn, h0, l0); vh.w = h0; vl.w = l0;
                const size_t off = (((size_t)bb * H_ + hh) * D_ + dd) * S_ + ss;
                *(ushort4*)&Vth[off] = vh;
                *(ushort4*)&Vtl[off] = vl;
            } else {
                u16t* __restrict__ Oh = (which == 0) ? Qh : Kh;
                u16t* __restrict__ Ol = (which == 0) ? Ql : Kl;
                #pragma unroll
                for (int j = 0; j < 4; ++j) {
                    u16t h0, l0;
                    split1(acc[mi][ni][j] + bn, h0, l0);
                    const size_t off = (((size_t)bb * H_ + hh) * S_ + ss + j) * D_ + dd;
                    Oh[off] = h0;
                    Ol[off] = l0;
                }
            }
        }
    }
}

// ---------------------------------------------------------------------------
// MFMA flash attention.  Block = (b,h, 64 q-rows), 4 waves; wave owns 16 q.
// Scores computed TRANSPOSED: C[k][q] = K.Q^T (A=K [s][d], B=Q [s][d]) so
// each lane holds all 64 k for one q -> softmax = in-reg + 2 shuffles.
// PV: ctx^T[d][q] = Vt.P^T (A=Vt [d][s], B=P from per-wave LDS).
// All GEMMs 3-term bf16 hi/lo split (error ~2^-18).
// ---------------------------------------------------------------------------
__global__ __launch_bounds__(256) void attn_mfma_kernel(
    const u16t* __restrict__ Qhg, const u16t* __restrict__ Qlg,
    const u16t* __restrict__ Khg, const u16t* __restrict__ Klg,
    const u16t* __restrict__ Vhg, const u16t* __restrict__ Vlg,
    const int*  __restrict__ ge,  const float* __restrict__ mask,
    const float* __restrict__ dpk, const float* __restrict__ dpv,
    float* __restrict__ out)
{
    __shared__ __align__(16) u16t Qh_s[64 * 72];
    __shared__ __align__(16) u16t Ql_s[64 * 72];
    __shared__ __align__(16) u16t Kh_s[64 * 72];
    __shared__ __align__(16) u16t Kl_s[64 * 72];
    __shared__ __align__(16) u16t Vh_s[64 * 72];
    __shared__ __align__(16) u16t Vl_s[64 * 72];
    __shared__ __align__(16) u16t P_s[4][2 * 16 * 72];   // per-wave P hi/lo; aliased as ctxT f32[64][17]
    __shared__ float ms[64];

    const int tid  = threadIdx.x;
    const int lane = tid & 63;
    const int wq   = tid >> 6;        // wave id -> q sub-block
    const int c    = lane & 15;       // frag row/col index
    const int g    = lane >> 4;       // k-chunk group
    const int bid  = blockIdx.x;
    const int bh   = bid >> 3;
    const int q0   = (bid & 7) * 64;
    const int b    = bh >> 4;
    const int h    = bh & (H_ - 1);

    u16t* Pwh = &P_s[wq][0];
    u16t* Pwl = &P_s[wq][16 * 72];

    // ---- prologue: stage Q tile ----
    {
        const int r0 = tid >> 2;
        const int o1 = (tid & 3) * 8;
        const int o2 = o1 + 32;
        const size_t qro = ((size_t)bh * S_ + q0 + r0) * D_;
        *(s16x8*)&Qh_s[r0 * 72 + o1] = *(const s16x8*)&Qhg[qro + o1];
        *(s16x8*)&Qh_s[r0 * 72 + o2] = *(const s16x8*)&Qhg[qro + o2];
        *(s16x8*)&Ql_s[r0 * 72 + o1] = *(const s16x8*)&Qlg[qro + o1];
        *(s16x8*)&Ql_s[r0 * 72 + o2] = *(const s16x8*)&Qlg[qro + o2];
    }
    __syncthreads();

    // ---- t_r = q . dp_k[r], r=1,2 (row 0 zeroed); lane keeps its q's pair ----
    float tq1 = 0.f, tq2 = 0.f;
    {
        const float d1 = dpk[D_ + lane];
        const float d2 = dpk[2 * D_ + lane];
        for (int r = 0; r < 16; ++r) {
            const int row = wq * 16 + r;
            const float qv = b2f(Qh_s[row * 72 + lane]) + b2f(Ql_s[row * 72 + lane]);
            float a1 = qv * d1, a2 = qv * d2;
            #pragma unroll
            for (int off = 32; off > 0; off >>= 1) {
                a1 += __shfl_xor(a1, off);
                a2 += __shfl_xor(a2, off);
            }
            if (r == c) { tq1 = a1; tq2 = a2; }
        }
    }

    const int aK = c * 72 + g * 8;                 // K / Vt frag base (row c)
    const int bQ = (wq * 16 + c) * 72 + g * 8;     // Q frag base
    const int bP = c * 72 + g * 8;                 // P frag base (wave-local)
    const size_t geoff = ((size_t)b * S_ + q0 + wq * 16 + c) * S_;

    float mrun = -INFINITY, lrun = 0.f, w1 = 0.f, w2 = 0.f;
    f32x4 ctx4[4];
    #pragma unroll
    for (int mi = 0; mi < 4; ++mi)
        #pragma unroll
        for (int e = 0; e < 4; ++e) ctx4[mi][e] = 0.f;

    for (int kt = 0; kt < S_ / 64; ++kt) {
        const int k0 = kt * 64;

        // ---- stage K and Vt tiles (+mask slice) ----
        {
            const int r0 = tid >> 2;
            const int o1 = (tid & 3) * 8;
            const int o2 = o1 + 32;
            const size_t kro = ((size_t)bh * S_ + k0 + r0) * D_;
            const size_t vro = ((size_t)bh * D_ + r0) * S_ + k0;
            *(s16x8*)&Kh_s[r0 * 72 + o1] = *(const s16x8*)&Khg[kro + o1];
            *(s16x8*)&Kh_s[r0 * 72 + o2] = *(const s16x8*)&Khg[kro + o2];
            *(s16x8*)&Kl_s[r0 * 72 + o1] = *(const s16x8*)&Klg[kro + o1];
            *(s16x8*)&Kl_s[r0 * 72 + o2] = *(const s16x8*)&Klg[kro + o2];
            *(s16x8*)&Vh_s[r0 * 72 + o1] = *(const s16x8*)&Vhg[vro + o1];
            *(s16x8*)&Vh_s[r0 * 72 + o2] = *(const s16x8*)&Vhg[vro + o2];
            *(s16x8*)&Vl_s[r0 * 72 + o1] = *(const s16x8*)&Vlg[vro + o1];
            *(s16x8*)&Vl_s[r0 * 72 + o2] = *(const s16x8*)&Vlg[vro + o2];
            if (tid < 16)
                *(float4*)&ms[tid * 4] = *(const float4*)&mask[(size_t)b * S_ + k0 + tid * 4];
        }
        __syncthreads();

        // ---- QK^T (transposed): s4[mi] rows k=mi*16+g*4+j, col q=c ----
        f32x4 s4[4];
        #pragma unroll
        for (int mi = 0; mi < 4; ++mi)
            #pragma unroll
            for (int e = 0; e < 4; ++e) s4[mi][e] = 0.f;

        #pragma unroll
        for (int ks = 0; ks < 2; ++ks) {
            const s16x8 qh_ = *(const s16x8*)&Qh_s[bQ + ks * 32];
            const s16x8 ql_ = *(const s16x8*)&Ql_s[bQ + ks * 32];
            s16x8 kh_[4], kl_[4];
            #pragma unroll
            for (int mi = 0; mi < 4; ++mi) {
                kh_[mi] = *(const s16x8*)&Kh_s[aK + mi * 1152 + ks * 32];
                kl_[mi] = *(const s16x8*)&Kl_s[aK + mi * 1152 + ks * 32];
            }
            #pragma unroll
            for (int mi = 0; mi < 4; ++mi)
                s4[mi] = __builtin_amdgcn_mfma_f32_16x16x32_bf16(kh_[mi], qh_, s4[mi], 0, 0, 0);
            #pragma unroll
            for (int mi = 0; mi < 4; ++mi)
                s4[mi] = __builtin_amdgcn_mfma_f32_16x16x32_bf16(kl_[mi], qh_, s4[mi], 0, 0, 0);
            #pragma unroll
            for (int mi = 0; mi < 4; ++mi)
                s4[mi] = __builtin_amdgcn_mfma_f32_16x16x32_bf16(kh_[mi], ql_, s4[mi], 0, 0, 0);
        }

        // ---- relation lookup + mask + online softmax (per lane: one q) ----
        float sv[4][4];
        int   gcode[4][4];
        float tmax = -INFINITY;
        #pragma unroll
        for (int mi = 0; mi < 4; ++mi) {
            const int4   gc = *(const int4*)&ge[geoff + k0 + mi * 16 + g * 4];
            const float4 mk = *(const float4*)&ms[mi * 16 + g * 4];
            const int   gg[4] = {gc.x, gc.y, gc.z, gc.w};
            const float mm[4] = {mk.x, mk.y, mk.z, mk.w};
            #pragma unroll
            for (int j = 0; j < 4; ++j) {
                const float t = (gg[j] == 1) ? tq1 : (gg[j] == 2) ? tq2 : 0.f;
                const float x = fmaf(s4[mi][j], 0.125f, t + mm[j]);
                sv[mi][j] = x;
                gcode[mi][j] = gg[j];
                tmax = fmaxf(tmax, x);
            }
        }
        tmax = fmaxf(tmax, __shfl_xor(tmax, 16));
        tmax = fmaxf(tmax, __shfl_xor(tmax, 32));

        const float mn    = fmaxf(mrun, tmax);
        const float alpha = __expf(mrun - mn);
        mrun = mn;

        float rs = 0.f, rb1 = 0.f, rb2 = 0.f;
        #pragma unroll
        for (int mi = 0; mi < 4; ++mi)
            #pragma unroll
            for (int j = 0; j < 4; ++j) {
                const float e = __expf(sv[mi][j] - mn);
                sv[mi][j] = e;
                rs += e;
                rb1 += (gcode[mi][j] == 1) ? e : 0.f;
                rb2 += (gcode[mi][j] == 2) ? e : 0.f;
            }
        rs  += __shfl_xor(rs, 16);  rs  += __shfl_xor(rs, 32);
        rb1 += __shfl_xor(rb1, 16); rb1 += __shfl_xor(rb1, 32);
        rb2 += __shfl_xor(rb2, 16); rb2 += __shfl_xor(rb2, 32);

        lrun = lrun * alpha + rs;
        w1   = w1   * alpha + rb1;
        w2   = w2   * alpha + rb2;
        #pragma unroll
        for (int mi = 0; mi < 4; ++mi) ctx4[mi] *= alpha;

        // ---- split P to bf16 hi/lo, write wave-local LDS [q][k] ----
        #pragma unroll
        for (int mi = 0; mi < 4; ++mi) {
            ushort4 ph, pl;
            u16t h0, l0;
            split1(sv[mi][0], h0, l0); ph.x = h0; pl.x = l0;
            split1(sv[mi][1], h0, l0); ph.y = h0; pl.y = l0;
            split1(sv[mi][2], h0, l0); ph.z = h0; pl.z = l0;
            split1(sv[mi][3], h0, l0); ph.w = h0; pl.w = l0;
            *(ushort4*)&Pwh[c * 72 + mi * 16 + g * 4] = ph;
            *(ushort4*)&Pwl[c * 72 + mi * 16 + g * 4] = pl;
        }

        // ---- PV: ctx^T[d][q] += Vt . P^T ----
        #pragma unroll
        for (int ks = 0; ks < 2; ++ks) {
            const s16x8 ph_ = *(const s16x8*)&Pwh[bP + ks * 32];
            const s16x8 pl_ = *(const s16x8*)&Pwl[bP + ks * 32];
            s16x8 vh_[4], vl_[4];
            #pragma unroll
            for (int mi = 0; mi < 4; ++mi) {
                vh_[mi] = *(const s16x8*)&Vh_s[aK + mi * 1152 + ks * 32];
                vl_[mi] = *(const s16x8*)&Vl_s[aK + mi * 1152 + ks * 32];
            }
            #pragma unroll
            for (int mi = 0; mi < 4; ++mi)
                ctx4[mi] = __builtin_amdgcn_mfma_f32_16x16x32_bf16(vh_[mi], ph_, ctx4[mi], 0, 0, 0);
            #pragma unroll
            for (int mi = 0; mi < 4; ++mi)
                ctx4[mi] = __builtin_amdgcn_mfma_f32_16x16x32_bf16(vl_[mi], ph_, ctx4[mi], 0, 0, 0);
            #pragma unroll
            for (int mi = 0; mi < 4; ++mi)
                ctx4[mi] = __builtin_amdgcn_mfma_f32_16x16x32_bf16(vh_[mi], pl_, ctx4[mi], 0, 0, 0);
        }
        __syncthreads();   // K/Vt reads done before next stage overwrites
    }

    // ---- epilogue: normalize + relation-value term; transpose via LDS ----
    const float inv = 1.0f / lrun;
    float* tb = (float*)&P_s[wq][0];   // [64 d][17] f32, per-wave region
    #pragma unroll
    for (int mi = 0; mi < 4; ++mi) {
        const float4 dk1 = *(const float4*)&dpv[D_ + mi * 16 + g * 4];
        const float4 dk2 = *(const float4*)&dpv[2 * D_ + mi * 16 + g * 4];
        const float a1[4] = {dk1.x, dk1.y, dk1.z, dk1.w};
        const float a2[4] = {dk2.x, dk2.y, dk2.z, dk2.w};
        #pragma unroll
        for (int j = 0; j < 4; ++j) {
            const float val = (ctx4[mi][j] + w1 * a1[j] + w2 * a2[j]) * inv;
            tb[(mi * 16 + g * 4 + j) * 17 + c] = val;
        }
    }
    __syncthreads();
    #pragma unroll
    for (int qq = 0; qq < 16; ++qq)
        out[((size_t)b * S_ + q0 + wq * 16 + qq) * (H_ * D_) + h * D_ + lane] =
            tb[lane * 17 + qq];
}

extern "C" void kernel_launch(void* const* d_in, const int* in_sizes, int n_in,
                              void* d_out, int out_size, void* d_ws, size_t ws_size,
                              hipStream_t stream)
{
    const float* hs   = (const float*)d_in[0];
    const float* mask = (const float*)d_in[1];
    const int*   ge   = (const int*)d_in[2];
    const float* Wq   = (const float*)d_in[3];
    const float* bq   = (const float*)d_in[4];
    const float* Wk   = (const float*)d_in[5];
    const float* bk   = (const float*)d_in[6];
    const float* Wv   = (const float*)d_in[7];
    const float* bv   = (const float*)d_in[8];
    const float* dpk  = (const float*)d_in[9];
    const float* dpv  = (const float*)d_in[10];
    float* out = (float*)d_out;

    const size_t per = (size_t)B_ * H_ * S_ * D_;   // 4,194,304
    const size_t nX  = (size_t)B_ * S_ * HID;       // 4,194,304
    const size_t nW  = (size_t)HID * HID;           // 1,048,576

    u16t* base = (u16t*)d_ws;
    u16t* Qh  = base;
    u16t* Ql  = Qh  + per;
    u16t* Kh  = Ql  + per;
    u16t* Kl  = Kh  + per;
    u16t* Vth = Kl  + per;
    u16t* Vtl = Vth + per;
    u16t* Xhi = Vtl + per;
    u16t* Xlo = Xhi + nX;
    u16t* Whi = Xlo + nX;
    u16t* Wlo = Whi + 3 * nW;

    conv_split_kernel<<<(int)(nX / 4 / 256), 256, 0, stream>>>(hs, Xhi, Xlo, (int)(nX / 4));
    conv_split_kernel<<<(int)(nW / 4 / 256), 256, 0, stream>>>(Wq, Whi,          Wlo,          (int)(nW / 4));
    conv_split_kernel<<<(int)(nW / 4 / 256), 256, 0, stream>>>(Wk, Whi + nW,     Wlo + nW,     (int)(nW / 4));
    conv_split_kernel<<<(int)(nW / 4 / 256), 256, 0, stream>>>(Wv, Whi + 2 * nW, Wlo + 2 * nW, (int)(nW / 4));

    dim3 gridG(HID / 128, (B_ * S_) / 128, 3);
    qkv_mfma_kernel<<<gridG, dim3(256), 0, stream>>>(
        Xhi, Xlo, Whi, Wlo, bq, bk, bv, Qh, Ql, Kh, Kl, Vth, Vtl);

    dim3 gridB(B_ * H_ * (S_ / 64));
    attn_mfma_kernel<<<gridB, dim3(256), 0, stream>>>(
        Qh, Ql, Kh, Kl, Vth, Vtl, ge, mask, dpk, dpv, out);
}